// Round 1
// baseline (332.084 us; speedup 1.0000x reference)
//
#include <hip/hip_runtime.h>
#include <hip/hip_cooperative_groups.h>

namespace cg = cooperative_groups;

#define MNODES 384
#define RTHRESH 0.05f
#define NWAVES 6      // waves (nodes) per block
#define NBLOCKS 256   // 256 blocks * 6 waves = 1536 nodes; 1 block/CU guaranteed resident

// ---------------------------------------------------------------------------
// Single cooperative kernel:
//   P0: adj (ballot-compacted lists -> LDS) + phi(t=0) -> phiA
//   grid.sync()
//   t=0..2: agg(t) + g(t)  [state in registers]  + phi(t+1) -> ping-pong buf
//           grid.sync() between steps
// Workspace layout (bytes):
//   phiA @ 0      : 1536*128 f32 (786432)
//   phiB @ 786432 : 1536*128 f32 (786432)
// ---------------------------------------------------------------------------

// phi[node][128] = relu(W3^T relu(W2^T relu(W1[3:6]^T s + b1) + b2) + b3)
// One wave per node; lane computes neurons lane and lane+64. H1/H2 are
// per-wave LDS: wave-internal DS ordering makes barriers unnecessary
// (validated bit-exact in a prior round).
__device__ __forceinline__ void phi_stage(
    const float* __restrict__ fW1, const float* __restrict__ fb1,
    const float* __restrict__ fW2, const float* __restrict__ fb2,
    const float* __restrict__ fW3, const float* __restrict__ fb3,
    float s0, float s1, float s2, int lane,
    float* __restrict__ H1, float* __restrict__ H2,
    float* __restrict__ phidst /* this node's 128-float row */)
{
    // Layer 1 (effective 3->64; rel slot of the edge input is exactly zero,
    // so rows 0..2 of fW1 are provably unused)
    float v = fb1[lane];
    v = fmaf(s0, fW1[3 * 64 + lane], v);
    v = fmaf(s1, fW1[4 * 64 + lane], v);
    v = fmaf(s2, fW1[5 * 64 + lane], v);
    H1[lane] = fmaxf(v, 0.0f);
    // Layer 2: 64 -> 128
    float a0 = fb2[lane], a1 = fb2[lane + 64];
#pragma unroll 16
    for (int c = 0; c < 64; ++c) {
        const float h = H1[c];
        a0 = fmaf(h, fW2[c * 128 + lane], a0);
        a1 = fmaf(h, fW2[c * 128 + lane + 64], a1);
    }
    H2[lane] = fmaxf(a0, 0.0f);
    H2[lane + 64] = fmaxf(a1, 0.0f);
    // Layer 3: 128 -> 128, final relu
    float c0 = fb3[lane], c1 = fb3[lane + 64];
#pragma unroll 16
    for (int c = 0; c < 128; ++c) {
        const float h = H2[c];
        c0 = fmaf(h, fW3[c * 128 + lane], c0);
        c1 = fmaf(h, fW3[c * 128 + lane + 64], c1);
    }
    phidst[lane] = fmaxf(c0, 0.0f);
    phidst[lane + 64] = fmaxf(c1, 0.0f);
}

__global__ __launch_bounds__(384) void fused_kernel(
    const float* __restrict__ x,
    const float* __restrict__ fW1, const float* __restrict__ fb1,
    const float* __restrict__ fW2, const float* __restrict__ fb2,
    const float* __restrict__ fW3, const float* __restrict__ fb3,
    const float* __restrict__ gW1, const float* __restrict__ gb1,
    const float* __restrict__ gW2, const float* __restrict__ gb2,
    const float* __restrict__ gW3, const float* __restrict__ gb3,
    float* __restrict__ phiA, float* __restrict__ phiB,
    float* __restrict__ outp)
{
    cg::grid_group grid = cg::this_grid();
    __shared__ float xs[MNODES * 3];
    __shared__ float work[NWAVES][224];              // aggL[128] | h1[64] | h2[32]; phi reuses [0..192)
    __shared__ unsigned short mlists[NWAVES][MNODES];

    const int tid = threadIdx.x;
    const int wv = tid >> 6, lane = tid & 63;
    const int node = __builtin_amdgcn_readfirstlane(blockIdx.x * NWAVES + wv);
    const int n = blockIdx.x >> 6;                   // 64 blocks per batch (384/6)
    const int i = node - n * MNODES;
    const int nbase = n * MNODES;

    for (int idx = tid; idx < MNODES * 3; idx += 384)
        xs[idx] = x[n * MNODES * 3 + idx];
    __syncthreads();

    // state lives in registers for the whole kernel (all lanes hold a copy)
    float st0 = xs[i * 3], st1 = xs[i * 3 + 1], st2 = xs[i * 3 + 2];

    // adjacency: ballot-compacted neighbor list, kept in LDS (owner-wave only)
    unsigned short* const ml = &mlists[wv][0];
    int nc = 0;
#pragma unroll
    for (int rep = 0; rep < 6; ++rep) {
        const int j = rep * 64 + lane;
        float dx = xs[j * 3] - st0;
        float dy = xs[j * 3 + 1] - st1;
        float dz = xs[j * 3 + 2] - st2;
        // match numpy rounding exactly (no fp-contract): (dx*dx + dy*dy) + dz*dz
        float d2 = __fadd_rn(__fadd_rn(__fmul_rn(dx, dx), __fmul_rn(dy, dy)),
                             __fmul_rn(dz, dz));
        const bool a = d2 < RTHRESH;
        const unsigned long long m = __ballot(a);
        if (a) ml[nc + __popcll(m & ((1ull << lane) - 1ull))] = (unsigned short)j;
        nc += (int)__popcll(m);
    }

    // phi(t=0) from x -> phiA
    phi_stage(fW1, fb1, fW2, fb2, fW3, fb3, st0, st1, st2, lane,
              &work[wv][0], &work[wv][64], phiA + (size_t)node * 128);

    __threadfence();
    grid.sync();

    const float* psrc = phiA;
    float* pdst = phiB;
    const int last = nc - 1;   // nc >= 1 always (self-edge: d2 = 0 < R)

    for (int t = 0; t < 3; ++t) {
        // agg: max over neighbors. phi >= 0 and non-neighbors contribute 0 in
        // the reference, so init 0 is exact. 8-wide with index clamping:
        // re-reading the last neighbor is harmless under max.
        const float* pb = psrc + (size_t)nbase * 128;
        float mx[8], px[8];
#pragma unroll
        for (int k = 0; k < 8; ++k) { mx[k] = 0.0f; px[k] = 0.0f; }
        for (int jj = 0; jj < nc; jj += 8) {
            const float* r[8];
#pragma unroll
            for (int k = 0; k < 8; ++k) {
                const int jc = jj + k;
                const int j = ml[jc < last ? jc : last];
                r[k] = pb + (size_t)j * 128;
            }
#pragma unroll
            for (int k = 0; k < 8; ++k) {
                mx[k] = fmaxf(mx[k], r[k][lane]);
                px[k] = fmaxf(px[k], r[k][lane + 64]);
            }
        }
        float* const aggL = &work[wv][0];
        float* const h1L  = &work[wv][128];
        float* const h2L  = &work[wv][192];
        aggL[lane] = fmaxf(fmaxf(fmaxf(mx[0], mx[1]), fmaxf(mx[2], mx[3])),
                           fmaxf(fmaxf(mx[4], mx[5]), fmaxf(mx[6], mx[7])));
        aggL[lane + 64] = fmaxf(fmaxf(fmaxf(px[0], px[1]), fmaxf(px[2], px[3])),
                                fmaxf(fmaxf(px[4], px[5]), fmaxf(px[6], px[7])));

        const float* gW1t = gW1 + t * 8192;
        const float* gb1t = gb1 + t * 64;
        const float* gW2t = gW2 + t * 2048;
        const float* gb2t = gb2 + t * 32;
        const float* gW3t = gW3 + t * 96;
        const float* gb3t = gb3 + t * 3;

        // g1: 128 -> 64
        float h = gb1t[lane];
#pragma unroll 16
        for (int c = 0; c < 128; ++c) h = fmaf(aggL[c], gW1t[c * 64 + lane], h);
        h1L[lane] = fmaxf(h, 0.0f);
        // g2: 64 -> 32
        if (lane < 32) {
            float v2 = gb2t[lane];
#pragma unroll 16
            for (int k = 0; k < 64; ++k) v2 = fmaf(h1L[k], gW2t[k * 32 + lane], v2);
            h2L[lane] = fmaxf(v2, 0.0f);
        }
        // g3: 32 -> 3, final relu, residual (state from registers)
        float ns = 0.0f;
        if (lane < 3) {
            const float sv = (lane == 0) ? st0 : (lane == 1) ? st1 : st2;
            float v3 = gb3t[lane];
#pragma unroll
            for (int q = 0; q < 32; ++q) v3 = fmaf(h2L[q], gW3t[q * 3 + lane], v3);
            ns = fmaxf(v3, 0.0f) + sv;
        }

        if (t == 2) {
            if (lane < 3) outp[node * 3 + lane] = ns;
        } else {
            st0 = __shfl(ns, 0); st1 = __shfl(ns, 1); st2 = __shfl(ns, 2);
            const int tn = t + 1;
            phi_stage(fW1 + tn * 384, fb1 + tn * 64,
                      fW2 + tn * 8192, fb2 + tn * 128,
                      fW3 + tn * 16384, fb3 + tn * 128,
                      st0, st1, st2, lane,
                      &work[wv][0], &work[wv][64], pdst + (size_t)node * 128);
            __threadfence();
            grid.sync();
            float* tmp = (float*)psrc; psrc = pdst; pdst = tmp;
        }
    }
}

extern "C" void kernel_launch(void* const* d_in, const int* in_sizes, int n_in,
                              void* d_out, int out_size, void* d_ws, size_t ws_size,
                              hipStream_t stream) {
    const float* x   = (const float*)d_in[0];
    // d_in[1..6] = hW1..hb3 : provably unused (delta MLP receives exact zeros)
    const float* fW1 = (const float*)d_in[7];
    const float* fb1 = (const float*)d_in[8];
    const float* fW2 = (const float*)d_in[9];
    const float* fb2 = (const float*)d_in[10];
    const float* fW3 = (const float*)d_in[11];
    const float* fb3 = (const float*)d_in[12];
    const float* gW1 = (const float*)d_in[13];
    const float* gb1 = (const float*)d_in[14];
    const float* gW2 = (const float*)d_in[15];
    const float* gb2 = (const float*)d_in[16];
    const float* gW3 = (const float*)d_in[17];
    const float* gb3 = (const float*)d_in[18];

    char* ws = (char*)d_ws;
    float* phiA = (float*)(ws + 0);
    float* phiB = (float*)(ws + 786432);
    float* outp = (float*)d_out;

    void* args[] = {
        (void*)&x,
        (void*)&fW1, (void*)&fb1, (void*)&fW2, (void*)&fb2, (void*)&fW3, (void*)&fb3,
        (void*)&gW1, (void*)&gb1, (void*)&gW2, (void*)&gb2, (void*)&gW3, (void*)&gb3,
        (void*)&phiA, (void*)&phiB, (void*)&outp
    };
    hipLaunchCooperativeKernel((const void*)fused_kernel,
                               dim3(NBLOCKS), dim3(64 * NWAVES), args, 0, stream);
}

// Round 2
// 139.918 us; speedup vs baseline: 2.3734x; 2.3734x over previous
//
#include <hip/hip_runtime.h>

#define MNODES 384
#define RTHRESH 0.05f
#define NWAVES 6     // nodes (waves) per block
#define NBLOCKS 256  // 256 blocks * 6 = 1536 nodes; exactly 1 block/CU

// ---------------------------------------------------------------------------
// 4 plain launches (kernel boundaries carry the cross-block phi dependency;
// cooperative fusion was tried and regressed 2.5x: device-scope fences for
// cross-XCD visibility invalidate L2 -> weights re-stream from L3/HBM).
//   K0: adj + phi(t=0) -> phiA
//   K1: agg0+g0 (-> stateA) + phi(t=1) -> phiB
//   K2: agg1+g1 (stateA -> stateB) + phi(t=2) -> phiA
//   K3: agg2+g2 -> d_out
// Workspace layout (bytes):
//   lists  @ 0        : 1536*384 u16  (1179648)
//   cnt    @ 1179648  : 1536 int      (6144)
//   phiA   @ 1185792  : 1536*128 f32  (786432)
//   phiB   @ 1972224  : 1536*128 f32  (786432)
//   stateA @ 2758656  : 1536*3 f32    (18432)
//   stateB @ 2777088  : 1536*3 f32    (18432)
// ---------------------------------------------------------------------------

// phi[node][128] = relu(W3^T relu(W2^T relu(W1[3:6]^T s + b1) + b2) + b3)
// One wave per node. PAIR-NEURON layout: lane computes neurons 2*lane and
// 2*lane+1, so each weight-pair load is one global_load_dwordx2 (halves VMEM
// instruction count vs the (lane, lane+64) split). Per-neuron accumulation
// order over c is unchanged -> bit-exact vs the verified baseline.
// H1/H2 are per-wave LDS: wave-internal DS ordering makes barriers
// unnecessary (validated bit-exact in a prior round).
__device__ __forceinline__ void phi_stage(
    const float* __restrict__ fW1, const float* __restrict__ fb1,
    const float* __restrict__ fW2, const float* __restrict__ fb2,
    const float* __restrict__ fW3, const float* __restrict__ fb3,
    float s0, float s1, float s2, int lane,
    float* __restrict__ H1, float* __restrict__ H2,
    float* __restrict__ phidst /* this node's 128-float row */)
{
    // Layer 1 (effective 3->64; rel slot of the edge input is exactly zero,
    // so rows 0..2 of fW1 are provably unused)
    float v = fb1[lane];
    v = fmaf(s0, fW1[3 * 64 + lane], v);
    v = fmaf(s1, fW1[4 * 64 + lane], v);
    v = fmaf(s2, fW1[5 * 64 + lane], v);
    H1[lane] = fmaxf(v, 0.0f);

    const int l2 = lane * 2;
    // Layer 2: 64 -> 128 (neurons l2, l2+1)
    const float2 b2 = *(const float2*)(fb2 + l2);
    float a0 = b2.x, a1 = b2.y;
#pragma unroll 16
    for (int c = 0; c < 64; ++c) {
        const float h = H1[c];
        const float2 w = *(const float2*)(fW2 + c * 128 + l2);
        a0 = fmaf(h, w.x, a0);
        a1 = fmaf(h, w.y, a1);
    }
    H2[l2] = fmaxf(a0, 0.0f);
    H2[l2 + 1] = fmaxf(a1, 0.0f);

    // Layer 3: 128 -> 128, final relu (neurons l2, l2+1)
    const float2 b3 = *(const float2*)(fb3 + l2);
    float c0 = b3.x, c1 = b3.y;
#pragma unroll 16
    for (int c = 0; c < 128; ++c) {
        const float h = H2[c];
        const float2 w = *(const float2*)(fW3 + c * 128 + l2);
        c0 = fmaf(h, w.x, c0);
        c1 = fmaf(h, w.y, c1);
    }
    *(float2*)(phidst + l2) = make_float2(fmaxf(c0, 0.0f), fmaxf(c1, 0.0f));
}

// K0: adjacency (ballot-compacted neighbor lists) + phi(t=0).
__global__ __launch_bounds__(384) void adj_phi0_kernel(
    const float* __restrict__ x,
    const float* __restrict__ fW1, const float* __restrict__ fb1,
    const float* __restrict__ fW2, const float* __restrict__ fb2,
    const float* __restrict__ fW3, const float* __restrict__ fb3,
    int* __restrict__ cnt, unsigned short* __restrict__ lists,
    float* __restrict__ phiA)
{
    __shared__ float xs[MNODES * 3];
    __shared__ float work[NWAVES][192];
    const int tid = threadIdx.x;
    const int wv = tid >> 6, lane = tid & 63;
    const int node = blockIdx.x * NWAVES + wv;   // [0,1536)
    const int n = blockIdx.x >> 6;               // 64 blocks per batch
    const int i = node - n * MNODES;

    for (int idx = tid; idx < MNODES * 3; idx += 384)
        xs[idx] = x[n * MNODES * 3 + idx];
    __syncthreads();

    const float s0 = xs[i * 3], s1 = xs[i * 3 + 1], s2 = xs[i * 3 + 2];
    unsigned short* ml = lists + (size_t)node * MNODES;
    int nc = 0;
#pragma unroll
    for (int rep = 0; rep < 6; ++rep) {
        const int j = rep * 64 + lane;
        float dx = xs[j * 3] - s0;
        float dy = xs[j * 3 + 1] - s1;
        float dz = xs[j * 3 + 2] - s2;
        // match numpy rounding exactly (no fp-contract): (dx*dx + dy*dy) + dz*dz
        float d2 = __fadd_rn(__fadd_rn(__fmul_rn(dx, dx), __fmul_rn(dy, dy)),
                             __fmul_rn(dz, dz));
        const bool a = d2 < RTHRESH;
        const unsigned long long m = __ballot(a);
        if (a) ml[nc + __popcll(m & ((1ull << lane) - 1ull))] = (unsigned short)j;
        nc += (int)__popcll(m);
    }
    if (lane == 0) cnt[node] = nc;

    phi_stage(fW1, fb1, fW2, fb2, fW3, fb3, s0, s1, s2, lane,
              &work[wv][0], &work[wv][64], phiA + (size_t)node * 128);
}

// K1..K3: agg(t)+g(t) (+ phi(t+1) when do_phi). Wave per node.
__global__ __launch_bounds__(384) void step_kernel(
    const float* __restrict__ phisrc, float* __restrict__ phidst,
    const int* __restrict__ cnt, const unsigned short* __restrict__ lists,
    const float* __restrict__ statesrc, float* __restrict__ statedst,
    const float* __restrict__ gW1, const float* __restrict__ gb1,
    const float* __restrict__ gW2, const float* __restrict__ gb2,
    const float* __restrict__ gW3, const float* __restrict__ gb3,
    const float* __restrict__ fW1n, const float* __restrict__ fb1n,
    const float* __restrict__ fW2n, const float* __restrict__ fb2n,
    const float* __restrict__ fW3n, const float* __restrict__ fb3n,
    int do_phi)
{
    __shared__ float work[NWAVES][224];  // aggL[128] | h1[64] | h2[32]; phi reuses [0..192)
    const int tid = threadIdx.x;
    const int wv = tid >> 6, lane = tid & 63;
    const int node = __builtin_amdgcn_readfirstlane(blockIdx.x * NWAVES + wv);
    const int nbase = (blockIdx.x >> 6) * MNODES;
    const int nc = cnt[node];
    const unsigned short* ml = lists + (size_t)node * MNODES;
    const float* pb = phisrc + (size_t)nbase * 128;
    float* const aggL = &work[wv][0];
    float* const h1L  = &work[wv][128];
    float* const h2L  = &work[wv][192];
    const int l2 = lane * 2;

    // agg: max over neighbors. phi >= 0 and non-neighbors contribute 0 in the
    // reference, so init 0 is exact. 8-wide with index clamping: reading the
    // last neighbor multiple times is harmless under max. nc >= 1 always
    // (self-edge: d2 = 0 < R). Pair-neuron layout -> one dwordx2 per row.
    float m[8], p[8];
#pragma unroll
    for (int k = 0; k < 8; ++k) { m[k] = 0.0f; p[k] = 0.0f; }
    const int last = nc - 1;
    for (int jj = 0; jj < nc; jj += 8) {
        const float* r[8];
#pragma unroll
        for (int k = 0; k < 8; ++k) {
            const int jc = jj + k;
            const int j = ml[jc < last ? jc : last];
            r[k] = pb + (size_t)j * 128;
        }
#pragma unroll
        for (int k = 0; k < 8; ++k) {
            const float2 v = *(const float2*)(r[k] + l2);
            m[k] = fmaxf(m[k], v.x);
            p[k] = fmaxf(p[k], v.y);
        }
    }
    aggL[l2] = fmaxf(fmaxf(fmaxf(m[0], m[1]), fmaxf(m[2], m[3])),
                     fmaxf(fmaxf(m[4], m[5]), fmaxf(m[6], m[7])));
    aggL[l2 + 1] = fmaxf(fmaxf(fmaxf(p[0], p[1]), fmaxf(p[2], p[3])),
                         fmaxf(fmaxf(p[4], p[5]), fmaxf(p[6], p[7])));

    // g1: 128 -> 64
    float h = gb1[lane];
#pragma unroll 16
    for (int c = 0; c < 128; ++c) h = fmaf(aggL[c], gW1[c * 64 + lane], h);
    h1L[lane] = fmaxf(h, 0.0f);
    // g2: 64 -> 32
    if (lane < 32) {
        float v2 = gb2[lane];
#pragma unroll 16
        for (int k = 0; k < 64; ++k) v2 = fmaf(h1L[k], gW2[k * 32 + lane], v2);
        h2L[lane] = fmaxf(v2, 0.0f);
    }
    // g3: 32 -> 3, final relu, residual
    float sv = 0.0f;
    if (lane < 3) sv = statesrc[node * 3 + lane];
    float ns = 0.0f;
    if (lane < 3) {
        float v3 = gb3[lane];
#pragma unroll
        for (int q = 0; q < 32; ++q) v3 = fmaf(h2L[q], gW3[q * 3 + lane], v3);
        ns = fmaxf(v3, 0.0f) + sv;
        statedst[node * 3 + lane] = ns;
    }
    if (do_phi) {
        const float s0 = __shfl(ns, 0), s1 = __shfl(ns, 1), s2 = __shfl(ns, 2);
        phi_stage(fW1n, fb1n, fW2n, fb2n, fW3n, fb3n, s0, s1, s2, lane,
                  &work[wv][0], &work[wv][64], phidst + (size_t)node * 128);
    }
}

extern "C" void kernel_launch(void* const* d_in, const int* in_sizes, int n_in,
                              void* d_out, int out_size, void* d_ws, size_t ws_size,
                              hipStream_t stream) {
    const float* x   = (const float*)d_in[0];
    // d_in[1..6] = hW1..hb3 : provably unused (delta MLP receives exact zeros)
    const float* fW1 = (const float*)d_in[7];
    const float* fb1 = (const float*)d_in[8];
    const float* fW2 = (const float*)d_in[9];
    const float* fb2 = (const float*)d_in[10];
    const float* fW3 = (const float*)d_in[11];
    const float* fb3 = (const float*)d_in[12];
    const float* gW1 = (const float*)d_in[13];
    const float* gb1 = (const float*)d_in[14];
    const float* gW2 = (const float*)d_in[15];
    const float* gb2 = (const float*)d_in[16];
    const float* gW3 = (const float*)d_in[17];
    const float* gb3 = (const float*)d_in[18];

    char* ws = (char*)d_ws;
    unsigned short* lists = (unsigned short*)(ws + 0);
    int* cnt              = (int*)(ws + 1179648);
    float* phiA           = (float*)(ws + 1185792);
    float* phiB           = (float*)(ws + 1972224);
    float* stateA         = (float*)(ws + 2758656);
    float* stateB         = (float*)(ws + 2777088);
    float* outp           = (float*)d_out;

    // K0: adj + phi0 -> phiA
    adj_phi0_kernel<<<NBLOCKS, 64 * NWAVES, 0, stream>>>(
        x, fW1, fb1, fW2, fb2, fW3, fb3, cnt, lists, phiA);
    // K1: agg0+g0 (x -> stateA) + phi1 -> phiB
    step_kernel<<<NBLOCKS, 64 * NWAVES, 0, stream>>>(
        phiA, phiB, cnt, lists, x, stateA,
        gW1, gb1, gW2, gb2, gW3, gb3,
        fW1 + 384, fb1 + 64, fW2 + 8192, fb2 + 128,
        fW3 + 16384, fb3 + 128, 1);
    // K2: agg1+g1 (stateA -> stateB) + phi2 -> phiA
    step_kernel<<<NBLOCKS, 64 * NWAVES, 0, stream>>>(
        phiB, phiA, cnt, lists, stateA, stateB,
        gW1 + 8192, gb1 + 64, gW2 + 2048, gb2 + 32,
        gW3 + 96, gb3 + 3,
        fW1 + 768, fb1 + 128, fW2 + 16384, fb2 + 256,
        fW3 + 32768, fb3 + 256, 1);
    // K3: agg2+g2 (stateB -> out)
    step_kernel<<<NBLOCKS, 64 * NWAVES, 0, stream>>>(
        phiA, phiB, cnt, lists, stateB, outp,
        gW1 + 16384, gb1 + 128, gW2 + 4096, gb2 + 64,
        gW3 + 192, gb3 + 6,
        fW1, fb1, fW2, fb2, fW3, fb3, 0);
}